// Round 11
// baseline (10998.399 us; speedup 1.0000x reference)
//
#include <hip/hip_runtime.h>
#include <cstdint>

typedef unsigned short u16;
typedef unsigned int   u32;
typedef __attribute__((ext_vector_type(2))) float f32x2;

#define NL 3
#define NC 4
#define NB 16
#define NT 4096
#define MR (NB*NT)   // 65536 rows

// ---------------- weight prep: Wih scaled by exp(-log_s), fp32 ----------------
__global__ void k_scale_wih_f32(const float* __restrict__ wih, const float* __restrict__ ls,
                                float* __restrict__ dst, int n){
    int i = blockIdx.x * 256 + threadIdx.x;
    if (i >= n) return;
    int lc = i / (192 * 256);          // 0..11 -> (layer*4 + channel)
    float sc = expf(-ls[lc]);
    dst[i] = wih[i] * sc;
}

// ---------------- GEMM fp32: C = act(A @ W^T + bias) -------------------------
// UNCHANGED from passing rounds 6-10.
__global__ __launch_bounds__(256) void k_gemm_f32(
    const float* __restrict__ A, const float* __restrict__ W,
    const float* __restrict__ bias, float* __restrict__ Cdst,
    int M, int N, int K, int act)
{
    __shared__ float sA[64][33];
    __shared__ float sB[64][33];

    const int tid = threadIdx.x;
    const int bm = blockIdx.x, bn = blockIdx.y;
    const int ty = tid >> 4;
    const int tx = tid & 15;

    float acc[4][4] = {};

    const int lr = tid >> 2;            // staging row 0..63
    const int lc = (tid & 3) * 8;       // staging col 0,8,16,24

    for (int kk = 0; kk < K; kk += 32) {
        const float* ap = A + (size_t)(bm * 64 + lr) * K + kk + lc;
        const float* bp = W + (size_t)(bn * 64 + lr) * K + kk + lc;
        __syncthreads();
        float4 a0 = *(const float4*)(ap);
        float4 a1 = *(const float4*)(ap + 4);
        float4 b0 = *(const float4*)(bp);
        float4 b1 = *(const float4*)(bp + 4);
        *(float4*)&sA[lr][lc]     = a0;
        *(float4*)&sA[lr][lc + 4] = a1;
        *(float4*)&sB[lr][lc]     = b0;
        *(float4*)&sB[lr][lc + 4] = b1;
        __syncthreads();

        #pragma unroll
        for (int k = 0; k < 32; k++) {
            float av[4], bv[4];
            #pragma unroll
            for (int i = 0; i < 4; i++) av[i] = sA[ty * 4 + i][k];
            #pragma unroll
            for (int j = 0; j < 4; j++) bv[j] = sB[tx * 4 + j][k];
            #pragma unroll
            for (int i = 0; i < 4; i++)
                #pragma unroll
                for (int j = 0; j < 4; j++)
                    acc[i][j] = fmaf(av[i], bv[j], acc[i][j]);
        }
    }

    #pragma unroll
    for (int i = 0; i < 4; i++) {
        int row = bm * 64 + ty * 4 + i;
        #pragma unroll
        for (int j = 0; j < 4; j++) {
            int col = bn * 64 + tx * 4 + j;
            float v = acc[i][j] + bias[col];
            if (act) v = tanhf(v);
            Cdst[(size_t)row * N + col] = v;
        }
    }
}

// ---------------- GRU scan: single wave, pk_fma, LDS h-broadcast, NO barrier -
// Lane j owns hidden unit j. h mirrored in LDS, read as 32 uniform-address
// ds_read_b64 pair-broadcasts. Single wave => no s_barrier needed: the
// hsh write -> next-iter read ordering is kept by compiler alias analysis +
// the per-wave in-order DS pipe. Removing the barrier removes the implicit
// s_waitcnt vmcnt(0) drain that serialized stores + prefetch each step (r10).
__device__ __forceinline__ float fsig(float x){
    return 1.0f / (1.0f + __expf(-x));
}
__device__ __forceinline__ float ftanh(float x){
    float e = __expf(-2.0f * fabsf(x));
    float t = (1.0f - e) / (1.0f + e);
    return copysignf(t, x);
}
__device__ __forceinline__ void pkfma(f32x2& acc, f32x2 a, f32x2 b){
    asm("v_pk_fma_f32 %0, %1, %2, %0" : "+v"(acc) : "v"(a), "v"(b));
}

__global__ __launch_bounds__(64, 1) void k_scanp(
    const float* __restrict__ ig,   // (bch*NT,768): row lb*NT+t, col c*192+g*64+j (bias added)
    const float* __restrict__ Whh,  // layer base: (C,192,64)
    const float* __restrict__ bnp,  // (C,64)
    const float* __restrict__ lsp,  // (C)
    const float* __restrict__ h0p,  // (C,B,64) layer base
    float* __restrict__ ynew,       // layer base: (C,B,T,64) f32 (d_out)
    float* __restrict__ xc,         // (MR,256) f32: concat-channel buffer
    int b0)
{
    const int c  = blockIdx.x;
    const int lb = blockIdx.y;
    const int b  = b0 + lb;
    const int j  = threadIdx.x;     // 0..63

    // 96 weight pairs per lane (192 f32): rows j / 64+j / 128+j of Whh
    f32x2 wr[32], wz[32], wn[32];
    {
        const float* pr = Whh + (size_t)(c * 192 +       j) * 64;
        const float* pz = Whh + (size_t)(c * 192 +  64 + j) * 64;
        const float* pn = Whh + (size_t)(c * 192 + 128 + j) * 64;
        #pragma unroll
        for (int i = 0; i < 32; i++) {
            wr[i] = *(const f32x2*)(pr + 2 * i);
            wz[i] = *(const f32x2*)(pz + 2 * i);
            wn[i] = *(const f32x2*)(pn + 2 * i);
        }
    }

    __shared__ float hsh[64];
    float hj = h0p[(c * NB + b) * 64 + j];
    hsh[j] = hj;                     // single wave: no barrier needed

    const float rs  = expf(-lsp[c]);     // 1/s
    const float bnj = bnp[c * 64 + j];

    const float* igp = ig + (size_t)(lb * NT) * 768 + c * 192;
    float* yp = ynew + ((size_t)(c * NB + b) * NT) * 64 + j;
    float* xp = xc + (size_t)(b * NT) * 256 + c * 64 + j;

    // distance-2 prefetch of the 3 ig streams
    float pr0 = igp[j],       pz0 = igp[64 + j],       pn0 = igp[128 + j];
    float pr1 = igp[768 + j], pz1 = igp[768 + 64 + j], pn1 = igp[768 + 128 + j];

    const f32x2* hp = (const f32x2*)hsh;

    for (int t = 0; t < NT; t++) {
        float igr = pr0, igz = pz0, ign = pn0;
        pr0 = pr1; pz0 = pz1; pn0 = pn1;
        if (t + 2 < NT) {
            const float* nx = igp + (size_t)(t + 2) * 768;
            pr1 = nx[j]; pz1 = nx[64 + j]; pn1 = nx[128 + j];
        }

        // 6 packed accumulator chains (2 per gate), 32 pair-broadcast reads
        f32x2 ar0 = {0.f, 0.f}, ar1 = {0.f, 0.f};
        f32x2 az0 = {0.f, 0.f}, az1 = {0.f, 0.f};
        f32x2 an0 = {0.f, 0.f}, an1 = {0.f, 0.f};
        #pragma unroll
        for (int i = 0; i < 32; i += 2) {
            f32x2 h0 = hp[i];
            pkfma(ar0, h0, wr[i]);
            pkfma(az0, h0, wz[i]);
            pkfma(an0, h0, wn[i]);
            f32x2 h1 = hp[i + 1];
            pkfma(ar1, h1, wr[i + 1]);
            pkfma(az1, h1, wz[i + 1]);
            pkfma(an1, h1, wn[i + 1]);
        }
        float accr = (ar0.x + ar0.y) + (ar1.x + ar1.y);
        float accz = (az0.x + az0.y) + (az1.x + az1.y);
        float accn = (an0.x + an0.y) + (an1.x + an1.y);

        float r  = fsig(igr + accr);
        float z  = fsig(igz + accz);
        float n  = ftanh(ign + r * (accn + bnj));
        float hn = n + z * (hj - n);
        float y  = hj + (hn - hj) * rs;     // (hn-h)/s + h

        hsh[j] = y;                          // in-order DS pipe: next-iter reads see it
        yp[(size_t)t * 64]  = y;
        xp[(size_t)t * 256] = y;
        hj = y;
    }
}

// ---------------- launch ----------------
extern "C" void kernel_launch(void* const* d_in, const int* in_sizes, int n_in,
                              void* d_out, int out_size, void* d_ws, size_t ws_size,
                              hipStream_t stream)
{
    const float* in_inputs = (const float*)d_in[0];
    const float* h0    = (const float*)d_in[1];
    const float* encW1 = (const float*)d_in[3];
    const float* encB1 = (const float*)d_in[4];
    const float* encW2 = (const float*)d_in[5];
    const float* encB2 = (const float*)d_in[6];
    const float* gWih  = (const float*)d_in[7];
    const float* gWhh  = (const float*)d_in[8];
    const float* gB    = (const float*)d_in[9];
    const float* gBn   = (const float*)d_in[10];
    const float* logS  = (const float*)d_in[11];
    const float* mW1   = (const float*)d_in[12];
    const float* mB1   = (const float*)d_in[13];
    const float* mW2   = (const float*)d_in[14];
    const float* mB2   = (const float*)d_in[15];

    float* out_f  = (float*)d_out;                    // (B,T,256) f32
    float* ynew_f = out_f + (size_t)MR * 256;         // (L,C,B,T,64) f32

    // ---- adaptive chunking: maximize batches-per-chunk within ws_size ----
    const size_t xa_b  = (size_t)MR * 256 * 4;                 // 67.11 MB
    const size_t xc_b  = xa_b;                                 // 67.11 MB
    const size_t wih_b = (size_t)NL * NC * 192 * 256 * 4;      // 2.36 MB
    int bch = 16;
    for (;;) {
        size_t igb = (size_t)bch * NT * 768 * 4;
        size_t r0  = igb > xa_b ? igb : xa_b;   // XB aliases region 0
        if (r0 + xa_b + xc_b + wih_b + 4096 <= ws_size || bch == 1) break;
        bch >>= 1;
    }
    const int nch = NB / bch;
    const int mch = bch * NT;

    char* ws = (char*)d_ws;
    size_t off = 0;
    auto alloc = [&](size_t bytes) -> void* {
        void* p = ws + off;
        off = (off + bytes + 255) & ~(size_t)255;
        return p;
    };
    size_t igb = (size_t)bch * NT * 768 * 4;
    float* IG  = (float*)alloc(igb > xa_b ? igb : xa_b);  // region 0
    float* XB  = IG;                                       // alias: lifetimes disjoint
    float* XA  = (float*)alloc(xa_b);
    float* XC  = (float*)alloc(xc_b);
    float* WIHs= (float*)alloc(wih_b);

    int nWih = NL * NC * 192 * 256;
    k_scale_wih_f32<<<(nWih + 255) / 256, 256, 0, stream>>>(gWih, logS, WIHs, nWih);

    dim3 blk(256);
    // encoder: XB = tanh(inputs @ W1^T + b1); XA = XB @ W2^T + b2
    k_gemm_f32<<<dim3(MR / 64, 256 / 64), blk, 0, stream>>>(in_inputs, encW1, encB1, XB, MR, 256, 128, 1);
    k_gemm_f32<<<dim3(MR / 64, 256 / 64), blk, 0, stream>>>(XB, encW2, encB2, XA, MR, 256, 256, 0);

    for (int l = 0; l < NL; l++) {
        for (int ch = 0; ch < nch; ch++) {
            k_gemm_f32<<<dim3(mch / 64, 768 / 64), blk, 0, stream>>>(
                XA + (size_t)ch * mch * 256, WIHs + (size_t)l * NC * 192 * 256,
                gB + l * 768, IG, mch, 768, 256, 0);
            k_scanp<<<dim3(NC, bch), dim3(64), 0, stream>>>(
                IG, gWhh + (size_t)l * NC * 192 * 64, gBn + l * NC * 64, logS + l * NC,
                h0 + (size_t)l * NC * NB * 64,
                ynew_f + (size_t)l * NC * NB * NT * 64, XC, ch * bch);
        }
        // inter-layer MLP (XB aliases IG; IG dead after scans consumed it)
        k_gemm_f32<<<dim3(MR / 64, 256 / 64), blk, 0, stream>>>(
            XC, mW1 + (size_t)l * 256 * 256, mB1 + l * 256, XB, MR, 256, 256, 1);
        k_gemm_f32<<<dim3(MR / 64, 256 / 64), blk, 0, stream>>>(
            XB, mW2 + (size_t)l * 256 * 256, mB2 + l * 256, XA, MR, 256, 256, 0);
    }
    // faithful to source: mlps[-1] applied a second time -> out (f32)
    k_gemm_f32<<<dim3(MR / 64, 256 / 64), blk, 0, stream>>>(
        XA, mW1 + (size_t)2 * 256 * 256, mB1 + 2 * 256, XB, MR, 256, 256, 1);
    k_gemm_f32<<<dim3(MR / 64, 256 / 64), blk, 0, stream>>>(
        XB, mW2 + (size_t)2 * 256 * 256, mB2 + 2 * 256, out_f, MR, 256, 256, 0);
}

// Round 12
// 10613.734 us; speedup vs baseline: 1.0362x; 1.0362x over previous
//
#include <hip/hip_runtime.h>
#include <cstdint>

typedef unsigned short u16;
typedef unsigned int   u32;

#define NL 3
#define NC 4
#define NB 16
#define NT 4096
#define MR (NB*NT)   // 65536 rows

__device__ __forceinline__ u16 f2bf(float f){
    u32 u = __float_as_uint(f);
    u32 r = u + 0x7fffu + ((u >> 16) & 1u);
    return (u16)(r >> 16);
}

// ---------------- weight prep: Wih scaled by exp(-log_s), fp32 ----------------
__global__ void k_scale_wih_f32(const float* __restrict__ wih, const float* __restrict__ ls,
                                float* __restrict__ dst, int n){
    int i = blockIdx.x * 256 + threadIdx.x;
    if (i >= n) return;
    int lc = i / (192 * 256);          // 0..11 -> (layer*4 + channel)
    float sc = expf(-ls[lc]);
    dst[i] = wih[i] * sc;
}

// ---------------- GEMM fp32: C = act(A @ W^T + bias) -------------------------
// UNCHANGED from passing rounds 6-11.
__global__ __launch_bounds__(256) void k_gemm_f32(
    const float* __restrict__ A, const float* __restrict__ W,
    const float* __restrict__ bias, float* __restrict__ Cdst,
    int M, int N, int K, int act)
{
    __shared__ float sA[64][33];
    __shared__ float sB[64][33];

    const int tid = threadIdx.x;
    const int bm = blockIdx.x, bn = blockIdx.y;
    const int ty = tid >> 4;
    const int tx = tid & 15;

    float acc[4][4] = {};

    const int lr = tid >> 2;            // staging row 0..63
    const int lc = (tid & 3) * 8;       // staging col 0,8,16,24

    for (int kk = 0; kk < K; kk += 32) {
        const float* ap = A + (size_t)(bm * 64 + lr) * K + kk + lc;
        const float* bp = W + (size_t)(bn * 64 + lr) * K + kk + lc;
        __syncthreads();
        float4 a0 = *(const float4*)(ap);
        float4 a1 = *(const float4*)(ap + 4);
        float4 b0 = *(const float4*)(bp);
        float4 b1 = *(const float4*)(bp + 4);
        *(float4*)&sA[lr][lc]     = a0;
        *(float4*)&sA[lr][lc + 4] = a1;
        *(float4*)&sB[lr][lc]     = b0;
        *(float4*)&sB[lr][lc + 4] = b1;
        __syncthreads();

        #pragma unroll
        for (int k = 0; k < 32; k++) {
            float av[4], bv[4];
            #pragma unroll
            for (int i = 0; i < 4; i++) av[i] = sA[ty * 4 + i][k];
            #pragma unroll
            for (int j = 0; j < 4; j++) bv[j] = sB[tx * 4 + j][k];
            #pragma unroll
            for (int i = 0; i < 4; i++)
                #pragma unroll
                for (int j = 0; j < 4; j++)
                    acc[i][j] = fmaf(av[i], bv[j], acc[i][j]);
        }
    }

    #pragma unroll
    for (int i = 0; i < 4; i++) {
        int row = bm * 64 + ty * 4 + i;
        #pragma unroll
        for (int j = 0; j < 4; j++) {
            int col = bn * 64 + tx * 4 + j;
            float v = acc[i][j] + bias[col];
            if (act) v = tanhf(v);
            Cdst[(size_t)row * N + col] = v;
        }
    }
}

// ---------------- GRU scan: single wave, v_dot2_f32_bf16, bf16 h-broadcast ---
// Lane j owns unit j. Weights as 96 packed-bf16x2 VGPRs (r/z/n rows). h
// broadcast via LDS as 32 bf16-pair words, read as 8 uniform ds_read_b128.
// f32 accumulate, f32 own-state hj, f32 gates/update. No barriers (1 wave).
__device__ __forceinline__ float fsig(float x){
    return 1.0f / (1.0f + __expf(-x));
}
__device__ __forceinline__ float ftanh(float x){
    float e = __expf(-2.0f * fabsf(x));
    float t = (1.0f - e) / (1.0f + e);
    return copysignf(t, x);
}
__device__ __forceinline__ void dot2(float& acc, u32 h2, u32 w2){
    asm("v_dot2_f32_bf16 %0, %1, %2, %0" : "+v"(acc) : "v"(h2), "v"(w2));
}

__global__ __launch_bounds__(64, 1) void k_scand(
    const float* __restrict__ ig,   // (bch*NT,768): row lb*NT+t, col c*192+g*64+j (bias added)
    const float* __restrict__ Whh,  // layer base: (C,192,64)
    const float* __restrict__ bnp,  // (C,64)
    const float* __restrict__ lsp,  // (C)
    const float* __restrict__ h0p,  // (C,B,64) layer base
    float* __restrict__ ynew,       // layer base: (C,B,T,64) f32 (d_out)
    float* __restrict__ xc,         // (MR,256) f32: concat-channel buffer
    int b0)
{
    const int c  = blockIdx.x;
    const int lb = blockIdx.y;
    const int b  = b0 + lb;
    const int j  = threadIdx.x;     // 0..63

    // pack this lane's 3 gate rows as bf16x2: 96 u32 total
    u32 wr[32], wz[32], wn[32];
    {
        const float* pr = Whh + (size_t)(c * 192 +       j) * 64;
        const float* pz = Whh + (size_t)(c * 192 +  64 + j) * 64;
        const float* pn = Whh + (size_t)(c * 192 + 128 + j) * 64;
        #pragma unroll
        for (int i = 0; i < 32; i++) {
            wr[i] = (u32)f2bf(pr[2*i]) | ((u32)f2bf(pr[2*i+1]) << 16);
            wz[i] = (u32)f2bf(pz[2*i]) | ((u32)f2bf(pz[2*i+1]) << 16);
            wn[i] = (u32)f2bf(pn[2*i]) | ((u32)f2bf(pn[2*i+1]) << 16);
        }
    }

    __shared__ u32 hshb[32];        // 64 bf16 h values, pair i = units (2i, 2i+1)
    float hj = h0p[(c * NB + b) * 64 + j];
    ((u16*)hshb)[j] = f2bf(hj);     // single wave: no barrier needed

    const float rs  = expf(-lsp[c]);     // 1/s
    const float bnj = bnp[c * 64 + j];

    const float* igp = ig + (size_t)(lb * NT) * 768 + c * 192;
    float* yp = ynew + ((size_t)(c * NB + b) * NT) * 64 + j;
    float* xp = xc + (size_t)(b * NT) * 256 + c * 64 + j;

    // distance-2 prefetch of the 3 ig streams
    float pr0 = igp[j],       pz0 = igp[64 + j],       pn0 = igp[128 + j];
    float pr1 = igp[768 + j], pz1 = igp[768 + 64 + j], pn1 = igp[768 + 128 + j];

    const uint4* hq = (const uint4*)hshb;   // 8 uniform b128 reads = all 64 h

    for (int t = 0; t < NT; t++) {
        float igr = pr0, igz = pz0, ign = pn0;
        pr0 = pr1; pz0 = pz1; pn0 = pn1;
        if (t + 2 < NT) {
            const float* nx = igp + (size_t)(t + 2) * 768;
            pr1 = nx[j]; pz1 = nx[64 + j]; pn1 = nx[128 + j];
        }

        // 6 chains (2 per gate), 96 v_dot2_f32_bf16
        float ar0 = 0.f, ar1 = 0.f, az0 = 0.f, az1 = 0.f, an0 = 0.f, an1 = 0.f;
        #pragma unroll
        for (int i = 0; i < 8; i++) {
            uint4 hv = hq[i];
            dot2(ar0, hv.x, wr[4*i]);     dot2(az0, hv.x, wz[4*i]);     dot2(an0, hv.x, wn[4*i]);
            dot2(ar1, hv.y, wr[4*i+1]);   dot2(az1, hv.y, wz[4*i+1]);   dot2(an1, hv.y, wn[4*i+1]);
            dot2(ar0, hv.z, wr[4*i+2]);   dot2(az0, hv.z, wz[4*i+2]);   dot2(an0, hv.z, wn[4*i+2]);
            dot2(ar1, hv.w, wr[4*i+3]);   dot2(az1, hv.w, wz[4*i+3]);   dot2(an1, hv.w, wn[4*i+3]);
        }
        float accr = ar0 + ar1;
        float accz = az0 + az1;
        float accn = an0 + an1;

        float r  = fsig(igr + accr);
        float z  = fsig(igz + accz);
        float n  = ftanh(ign + r * (accn + bnj));
        float hn = n + z * (hj - n);
        float y  = hj + (hn - hj) * rs;     // (hn-h)/s + h

        ((u16*)hshb)[j] = f2bf(y);           // in-order DS pipe orders vs next reads
        yp[(size_t)t * 64]  = y;
        xp[(size_t)t * 256] = y;
        hj = y;
    }
}

// ---------------- launch ----------------
extern "C" void kernel_launch(void* const* d_in, const int* in_sizes, int n_in,
                              void* d_out, int out_size, void* d_ws, size_t ws_size,
                              hipStream_t stream)
{
    const float* in_inputs = (const float*)d_in[0];
    const float* h0    = (const float*)d_in[1];
    const float* encW1 = (const float*)d_in[3];
    const float* encB1 = (const float*)d_in[4];
    const float* encW2 = (const float*)d_in[5];
    const float* encB2 = (const float*)d_in[6];
    const float* gWih  = (const float*)d_in[7];
    const float* gWhh  = (const float*)d_in[8];
    const float* gB    = (const float*)d_in[9];
    const float* gBn   = (const float*)d_in[10];
    const float* logS  = (const float*)d_in[11];
    const float* mW1   = (const float*)d_in[12];
    const float* mB1   = (const float*)d_in[13];
    const float* mW2   = (const float*)d_in[14];
    const float* mB2   = (const float*)d_in[15];

    float* out_f  = (float*)d_out;                    // (B,T,256) f32
    float* ynew_f = out_f + (size_t)MR * 256;         // (L,C,B,T,64) f32

    // ---- adaptive chunking: maximize batches-per-chunk within ws_size ----
    const size_t xa_b  = (size_t)MR * 256 * 4;                 // 67.11 MB
    const size_t xc_b  = xa_b;                                 // 67.11 MB
    const size_t wih_b = (size_t)NL * NC * 192 * 256 * 4;      // 2.36 MB
    int bch = 16;
    for (;;) {
        size_t igb = (size_t)bch * NT * 768 * 4;
        size_t r0  = igb > xa_b ? igb : xa_b;   // XB aliases region 0
        if (r0 + xa_b + xc_b + wih_b + 4096 <= ws_size || bch == 1) break;
        bch >>= 1;
    }
    const int nch = NB / bch;
    const int mch = bch * NT;

    char* ws = (char*)d_ws;
    size_t off = 0;
    auto alloc = [&](size_t bytes) -> void* {
        void* p = ws + off;
        off = (off + bytes + 255) & ~(size_t)255;
        return p;
    };
    size_t igb = (size_t)bch * NT * 768 * 4;
    float* IG  = (float*)alloc(igb > xa_b ? igb : xa_b);  // region 0
    float* XB  = IG;                                       // alias: lifetimes disjoint
    float* XA  = (float*)alloc(xa_b);
    float* XC  = (float*)alloc(xc_b);
    float* WIHs= (float*)alloc(wih_b);

    int nWih = NL * NC * 192 * 256;
    k_scale_wih_f32<<<(nWih + 255) / 256, 256, 0, stream>>>(gWih, logS, WIHs, nWih);

    dim3 blk(256);
    // encoder: XB = tanh(inputs @ W1^T + b1); XA = XB @ W2^T + b2
    k_gemm_f32<<<dim3(MR / 64, 256 / 64), blk, 0, stream>>>(in_inputs, encW1, encB1, XB, MR, 256, 128, 1);
    k_gemm_f32<<<dim3(MR / 64, 256 / 64), blk, 0, stream>>>(XB, encW2, encB2, XA, MR, 256, 256, 0);

    for (int l = 0; l < NL; l++) {
        for (int ch = 0; ch < nch; ch++) {
            k_gemm_f32<<<dim3(mch / 64, 768 / 64), blk, 0, stream>>>(
                XA + (size_t)ch * mch * 256, WIHs + (size_t)l * NC * 192 * 256,
                gB + l * 768, IG, mch, 768, 256, 0);
            k_scand<<<dim3(NC, bch), dim3(64), 0, stream>>>(
                IG, gWhh + (size_t)l * NC * 192 * 64, gBn + l * NC * 64, logS + l * NC,
                h0 + (size_t)l * NC * NB * 64,
                ynew_f + (size_t)l * NC * NB * NT * 64, XC, ch * bch);
        }
        // inter-layer MLP (XB aliases IG; IG dead after scans consumed it)
        k_gemm_f32<<<dim3(MR / 64, 256 / 64), blk, 0, stream>>>(
            XC, mW1 + (size_t)l * 256 * 256, mB1 + l * 256, XB, MR, 256, 256, 1);
        k_gemm_f32<<<dim3(MR / 64, 256 / 64), blk, 0, stream>>>(
            XB, mW2 + (size_t)l * 256 * 256, mB2 + l * 256, XA, MR, 256, 256, 0);
    }
    // faithful to source: mlps[-1] applied a second time -> out (f32)
    k_gemm_f32<<<dim3(MR / 64, 256 / 64), blk, 0, stream>>>(
        XA, mW1 + (size_t)2 * 256 * 256, mB1 + 2 * 256, XB, MR, 256, 256, 1);
    k_gemm_f32<<<dim3(MR / 64, 256 / 64), blk, 0, stream>>>(
        XB, mW2 + (size_t)2 * 256 * 256, mB2 + 2 * 256, out_f, MR, 256, 256, 0);
}

// Round 13
// 8383.054 us; speedup vs baseline: 1.3120x; 1.2661x over previous
//
#include <hip/hip_runtime.h>
#include <cstdint>

typedef unsigned short u16;
typedef unsigned int   u32;

#define NL 3
#define NC 4
#define NB 16
#define NT 4096
#define MR (NB*NT)   // 65536 rows

__device__ __forceinline__ u16 f2bf(float f){
    u32 u = __float_as_uint(f);
    u32 r = u + 0x7fffu + ((u >> 16) & 1u);
    return (u16)(r >> 16);
}

// ---------------- weight prep: Wih scaled by exp(-log_s), fp32 ----------------
__global__ void k_scale_wih_f32(const float* __restrict__ wih, const float* __restrict__ ls,
                                float* __restrict__ dst, int n){
    int i = blockIdx.x * 256 + threadIdx.x;
    if (i >= n) return;
    int lc = i / (192 * 256);          // 0..11 -> (layer*4 + channel)
    float sc = expf(-ls[lc]);
    dst[i] = wih[i] * sc;
}

// ---------------- GEMM fp32: C = act(A @ W^T + bias) -------------------------
// AY=0: A (M,K) row-major. AY=1: A in ynew layout (C,B,T,64): col k -> c=k>>6,
// u=k&63; addr = base + (k>>6)*MR*64 + row*64 + (k&63). All 8-col staging spans
// stay within one c-block (64-aligned). Math identical to rounds 6-12.
template<int AY>
__global__ __launch_bounds__(256) void k_gemm_f32(
    const float* __restrict__ A, const float* __restrict__ W,
    const float* __restrict__ bias, float* __restrict__ Cdst,
    int M, int N, int K, int act)
{
    __shared__ float sA[64][33];
    __shared__ float sB[64][33];

    const int tid = threadIdx.x;
    const int bm = blockIdx.x, bn = blockIdx.y;
    const int ty = tid >> 4;
    const int tx = tid & 15;

    float acc[4][4] = {};

    const int lr = tid >> 2;            // staging row 0..63
    const int lc = (tid & 3) * 8;       // staging col 0,8,16,24

    for (int kk = 0; kk < K; kk += 32) {
        const float* ap;
        if (AY) {
            int col = kk + lc;
            ap = A + (size_t)(col >> 6) * ((size_t)MR * 64)
                   + (size_t)(bm * 64 + lr) * 64 + (col & 63);
        } else {
            ap = A + (size_t)(bm * 64 + lr) * K + kk + lc;
        }
        const float* bp = W + (size_t)(bn * 64 + lr) * K + kk + lc;
        __syncthreads();
        float4 a0 = *(const float4*)(ap);
        float4 a1 = *(const float4*)(ap + 4);
        float4 b0 = *(const float4*)(bp);
        float4 b1 = *(const float4*)(bp + 4);
        *(float4*)&sA[lr][lc]     = a0;
        *(float4*)&sA[lr][lc + 4] = a1;
        *(float4*)&sB[lr][lc]     = b0;
        *(float4*)&sB[lr][lc + 4] = b1;
        __syncthreads();

        #pragma unroll
        for (int k = 0; k < 32; k++) {
            float av[4], bv[4];
            #pragma unroll
            for (int i = 0; i < 4; i++) av[i] = sA[ty * 4 + i][k];
            #pragma unroll
            for (int j = 0; j < 4; j++) bv[j] = sB[tx * 4 + j][k];
            #pragma unroll
            for (int i = 0; i < 4; i++)
                #pragma unroll
                for (int j = 0; j < 4; j++)
                    acc[i][j] = fmaf(av[i], bv[j], acc[i][j]);
        }
    }

    #pragma unroll
    for (int i = 0; i < 4; i++) {
        int row = bm * 64 + ty * 4 + i;
        #pragma unroll
        for (int j = 0; j < 4; j++) {
            int col = bn * 64 + tx * 4 + j;
            float v = acc[i][j] + bias[col];
            if (act) v = tanhf(v);
            Cdst[(size_t)row * N + col] = v;
        }
    }
}

// ---------------- GRU scan: dot2 + 8-step store batching + deep prefetch -----
// Single wave per (c,b). Weights 96 packed-bf16x2 VGPRs. h broadcast via LDS
// (8 uniform ds_read_b128). y buffered in a 2KB LDS ring, flushed as 2
// coalesced dwordx4/lane per 8 steps. ig prefetched distance-8 via register
// double-buffer (24 loads in flight -> vmcnt waits are shallow).
__device__ __forceinline__ float fsig(float x){
    return 1.0f / (1.0f + __expf(-x));
}
__device__ __forceinline__ float ftanh(float x){
    float e = __expf(-2.0f * fabsf(x));
    float t = (1.0f - e) / (1.0f + e);
    return copysignf(t, x);
}
__device__ __forceinline__ void dot2(float& acc, u32 h2, u32 w2){
    asm("v_dot2_f32_bf16 %0, %1, %2, %0" : "+v"(acc) : "v"(h2), "v"(w2));
}

__global__ __launch_bounds__(64, 1) void k_scanb(
    const float* __restrict__ ig,   // (bch*NT,768): row lb*NT+t, col c*192+g*64+j (bias added)
    const float* __restrict__ Whh,  // layer base: (C,192,64)
    const float* __restrict__ bnp,  // (C,64)
    const float* __restrict__ lsp,  // (C)
    const float* __restrict__ h0p,  // (C,B,64) layer base
    float* __restrict__ ynew,       // layer base: (C,B,T,64) f32 (d_out)
    int b0)
{
    const int c  = blockIdx.x;
    const int lb = blockIdx.y;
    const int b  = b0 + lb;
    const int j  = threadIdx.x;     // 0..63

    // pack this lane's 3 gate rows as bf16x2: 96 u32
    u32 wr[32], wz[32], wn[32];
    {
        const float* pr = Whh + (size_t)(c * 192 +       j) * 64;
        const float* pz = Whh + (size_t)(c * 192 +  64 + j) * 64;
        const float* pn = Whh + (size_t)(c * 192 + 128 + j) * 64;
        #pragma unroll
        for (int i = 0; i < 32; i++) {
            wr[i] = (u32)f2bf(pr[2*i]) | ((u32)f2bf(pr[2*i+1]) << 16);
            wz[i] = (u32)f2bf(pz[2*i]) | ((u32)f2bf(pz[2*i+1]) << 16);
            wn[i] = (u32)f2bf(pn[2*i]) | ((u32)f2bf(pn[2*i+1]) << 16);
        }
    }

    __shared__ u32 hshb[32];        // 64 bf16 h values
    __shared__ float ring[512];     // 8 steps x 64 units
    float hj = h0p[(c * NB + b) * 64 + j];
    ((u16*)hshb)[j] = f2bf(hj);     // single wave: no barrier needed

    const float rs  = expf(-lsp[c]);     // 1/s
    const float bnj = bnp[c * 64 + j];

    const float* igp = ig + (size_t)(lb * NT) * 768 + c * 192;
    float* yrow = ynew + (size_t)(c * NB + b) * NT * 64;

    const uint4* hq = (const uint4*)hshb;   // 8 uniform b128 reads = all 64 h

    float A0[8], A1[8], A2[8], B0[8], B1[8], B2[8];
    #pragma unroll
    for (int s = 0; s < 8; s++) {
        const float* p = igp + (size_t)s * 768;
        A0[s] = p[j]; A1[s] = p[64 + j]; A2[s] = p[128 + j];
    }

    auto step = [&](float igr, float igz, float ign, int s){
        float ar0 = 0.f, ar1 = 0.f, az0 = 0.f, az1 = 0.f, an0 = 0.f, an1 = 0.f;
        #pragma unroll
        for (int i = 0; i < 8; i++) {
            uint4 hv = hq[i];
            dot2(ar0, hv.x, wr[4*i]);     dot2(az0, hv.x, wz[4*i]);     dot2(an0, hv.x, wn[4*i]);
            dot2(ar1, hv.y, wr[4*i+1]);   dot2(az1, hv.y, wz[4*i+1]);   dot2(an1, hv.y, wn[4*i+1]);
            dot2(ar0, hv.z, wr[4*i+2]);   dot2(az0, hv.z, wz[4*i+2]);   dot2(an0, hv.z, wn[4*i+2]);
            dot2(ar1, hv.w, wr[4*i+3]);   dot2(az1, hv.w, wz[4*i+3]);   dot2(an1, hv.w, wn[4*i+3]);
        }
        float r  = fsig(igr + (ar0 + ar1));
        float z  = fsig(igz + (az0 + az1));
        float n  = ftanh(ign + r * ((an0 + an1) + bnj));
        float hn = n + z * (hj - n);
        float y  = hj + (hn - hj) * rs;     // (hn-h)/s + h
        ((u16*)hshb)[j] = f2bf(y);           // in-order DS pipe orders vs next reads
        ring[s * 64 + j] = y;
        hj = y;
    };
    auto flush = [&](float* dst){
        float4 v0 = *(const float4*)&ring[4 * j];
        float4 v1 = *(const float4*)&ring[256 + 4 * j];
        *(float4*)(dst + 4 * j)       = v0;
        *(float4*)(dst + 256 + 4 * j) = v1;
    };

    for (int t0 = 0; t0 < NT; t0 += 16) {
        // half 1: load t0+8.. into B, process t0.. from A
        #pragma unroll
        for (int s = 0; s < 8; s++) {
            const float* p = igp + (size_t)(t0 + 8 + s) * 768;
            B0[s] = p[j]; B1[s] = p[64 + j]; B2[s] = p[128 + j];
        }
        #pragma unroll
        for (int s = 0; s < 8; s++) step(A0[s], A1[s], A2[s], s);
        flush(yrow + (size_t)t0 * 64);

        // half 2: load t0+16.. into A (guarded), process t0+8.. from B
        if (t0 + 16 < NT) {
            #pragma unroll
            for (int s = 0; s < 8; s++) {
                const float* p = igp + (size_t)(t0 + 16 + s) * 768;
                A0[s] = p[j]; A1[s] = p[64 + j]; A2[s] = p[128 + j];
            }
        }
        #pragma unroll
        for (int s = 0; s < 8; s++) step(B0[s], B1[s], B2[s], s);
        flush(yrow + (size_t)(t0 + 8) * 64);
    }
}

// ---------------- launch ----------------
extern "C" void kernel_launch(void* const* d_in, const int* in_sizes, int n_in,
                              void* d_out, int out_size, void* d_ws, size_t ws_size,
                              hipStream_t stream)
{
    const float* in_inputs = (const float*)d_in[0];
    const float* h0    = (const float*)d_in[1];
    const float* encW1 = (const float*)d_in[3];
    const float* encB1 = (const float*)d_in[4];
    const float* encW2 = (const float*)d_in[5];
    const float* encB2 = (const float*)d_in[6];
    const float* gWih  = (const float*)d_in[7];
    const float* gWhh  = (const float*)d_in[8];
    const float* gB    = (const float*)d_in[9];
    const float* gBn   = (const float*)d_in[10];
    const float* logS  = (const float*)d_in[11];
    const float* mW1   = (const float*)d_in[12];
    const float* mB1   = (const float*)d_in[13];
    const float* mW2   = (const float*)d_in[14];
    const float* mB2   = (const float*)d_in[15];

    float* out_f  = (float*)d_out;                    // (B,T,256) f32
    float* ynew_f = out_f + (size_t)MR * 256;         // (L,C,B,T,64) f32

    // ---- adaptive chunking (XC eliminated: MLP reads ynew directly) ----
    const size_t xa_b  = (size_t)MR * 256 * 4;                 // 67.11 MB
    const size_t wih_b = (size_t)NL * NC * 192 * 256 * 4;      // 2.36 MB
    int bch = 16;
    for (;;) {
        size_t igb = (size_t)bch * NT * 768 * 4;
        size_t r0  = igb > xa_b ? igb : xa_b;   // XB aliases region 0
        if (r0 + xa_b + wih_b + 4096 <= ws_size || bch == 1) break;
        bch >>= 1;
    }
    const int nch = NB / bch;
    const int mch = bch * NT;

    char* ws = (char*)d_ws;
    size_t off = 0;
    auto alloc = [&](size_t bytes) -> void* {
        void* p = ws + off;
        off = (off + bytes + 255) & ~(size_t)255;
        return p;
    };
    size_t igb = (size_t)bch * NT * 768 * 4;
    float* IG  = (float*)alloc(igb > xa_b ? igb : xa_b);  // region 0
    float* XB  = IG;                                       // alias: lifetimes disjoint
    float* XA  = (float*)alloc(xa_b);
    float* WIHs= (float*)alloc(wih_b);

    int nWih = NL * NC * 192 * 256;
    k_scale_wih_f32<<<(nWih + 255) / 256, 256, 0, stream>>>(gWih, logS, WIHs, nWih);

    dim3 blk(256);
    // encoder: XB = tanh(inputs @ W1^T + b1); XA = XB @ W2^T + b2
    k_gemm_f32<0><<<dim3(MR / 64, 256 / 64), blk, 0, stream>>>(in_inputs, encW1, encB1, XB, MR, 256, 128, 1);
    k_gemm_f32<0><<<dim3(MR / 64, 256 / 64), blk, 0, stream>>>(XB, encW2, encB2, XA, MR, 256, 256, 0);

    for (int l = 0; l < NL; l++) {
        float* ylayer = ynew_f + (size_t)l * NC * NB * NT * 64;
        for (int ch = 0; ch < nch; ch++) {
            k_gemm_f32<0><<<dim3(mch / 64, 768 / 64), blk, 0, stream>>>(
                XA + (size_t)ch * mch * 256, WIHs + (size_t)l * NC * 192 * 256,
                gB + l * 768, IG, mch, 768, 256, 0);
            k_scanb<<<dim3(NC, bch), dim3(64), 0, stream>>>(
                IG, gWhh + (size_t)l * NC * 192 * 64, gBn + l * NC * 64, logS + l * NC,
                h0 + (size_t)l * NC * NB * 64, ylayer, ch * bch);
        }
        // inter-layer MLP reads A straight from ynew layout (XC fused away)
        k_gemm_f32<1><<<dim3(MR / 64, 256 / 64), blk, 0, stream>>>(
            ylayer, mW1 + (size_t)l * 256 * 256, mB1 + l * 256, XB, MR, 256, 256, 1);
        k_gemm_f32<0><<<dim3(MR / 64, 256 / 64), blk, 0, stream>>>(
            XB, mW2 + (size_t)l * 256 * 256, mB2 + l * 256, XA, MR, 256, 256, 0);
    }
    // faithful to source: mlps[-1] applied a second time -> out (f32)
    k_gemm_f32<0><<<dim3(MR / 64, 256 / 64), blk, 0, stream>>>(
        XA, mW1 + (size_t)2 * 256 * 256, mB1 + 2 * 256, XB, MR, 256, 256, 1);
    k_gemm_f32<0><<<dim3(MR / 64, 256 / 64), blk, 0, stream>>>(
        XB, mW2 + (size_t)2 * 256 * 256, mB2 + 2 * 256, out_f, MR, 256, 256, 0);
}

// Round 14
// 5598.466 us; speedup vs baseline: 1.9645x; 1.4974x over previous
//
#include <hip/hip_runtime.h>
#include <cstdint>

typedef unsigned short u16;
typedef unsigned int   u32;
typedef __attribute__((ext_vector_type(4))) float f32x4;
typedef __attribute__((ext_vector_type(8))) short s16x8;

#define NL 3
#define NC 4
#define NB 16
#define NT 4096
#define MR (NB*NT)   // 65536 rows

__device__ __forceinline__ u16 f2bf(float f){
    u32 u = __float_as_uint(f);
    u32 r = u + 0x7fffu + ((u >> 16) & 1u);
    return (u16)(r >> 16);
}
__device__ __forceinline__ u32 pk2(float x, float y){
    return (u32)f2bf(x) | ((u32)f2bf(y) << 16);
}

// ---------------- weight prep ----------------
__global__ void k_w_to_bf16(const float* __restrict__ src, u16* __restrict__ dst, int n){
    int i = blockIdx.x * 256 + threadIdx.x;
    if (i < n) dst[i] = f2bf(src[i]);
}
__global__ void k_scale_wih_bf16(const float* __restrict__ wih, const float* __restrict__ ls,
                                 u16* __restrict__ dst, int n){
    int i = blockIdx.x * 256 + threadIdx.x;
    if (i >= n) return;
    int lc = i / (192 * 256);          // 0..11 -> (layer*4 + channel)
    float sc = expf(-ls[lc]);
    dst[i] = f2bf(wih[i] * sc);
}

// ---------------- MFMA GEMM: C = act(A @ W^T + bias) -------------------------
// A f32 (AY=0: (M,K) row-major; AY=1: ynew layout (C,B,T,64), col k -> block
// k>>6, unit k&63) converted to bf16 during LDS staging. W (N,K) bf16.
// Output f32. 128x128 tile, BK=32, 256 thr / 4 waves. Fragment + C/D mapping
// exactly as round-1 (proven bit-equivalent to the scalar GEMM in r1<->r2).
template<int AY>
__global__ __launch_bounds__(256) void k_gemm_mfma(
    const float* __restrict__ A, const u16* __restrict__ W,
    const float* __restrict__ bias, float* __restrict__ Cdst,
    int M, int N, int K, int act)
{
    __shared__ u16 lA[128][40];
    __shared__ u16 lB[128][40];

    const int tid  = threadIdx.x;
    const int bm   = blockIdx.x, bn = blockIdx.y;
    const int lane = tid & 63;
    const int wv   = tid >> 6;
    const int wm   = wv >> 1, wn = wv & 1;
    const int r    = tid >> 1;          // 0..127 staging row
    const int kh   = (tid & 1) * 16;    // staging k-offset (elements)

    f32x4 acc[4][4];
    #pragma unroll
    for (int i = 0; i < 4; i++)
        #pragma unroll
        for (int j = 0; j < 4; j++)
            acc[i][j] = f32x4{0.f, 0.f, 0.f, 0.f};

    const int fr = lane & 15;
    const int fk = (lane >> 4) * 8;

    for (int kk = 0; kk < K; kk += 32) {
        const float* ap;
        if (AY) {
            int col = kk + kh;          // multiple of 16, span 16: one 64-block
            ap = A + (size_t)(col >> 6) * ((size_t)MR * 64)
                   + (size_t)(bm * 128 + r) * 64 + (col & 63);
        } else {
            ap = A + (size_t)(bm * 128 + r) * K + kk + kh;
        }
        const u16* bp = W + (size_t)(bn * 128 + r) * K + kk + kh;

        float4 a0 = *(const float4*)(ap);
        float4 a1 = *(const float4*)(ap + 4);
        float4 a2 = *(const float4*)(ap + 8);
        float4 a3 = *(const float4*)(ap + 12);
        uint4  b0 = *(const uint4*)(bp);
        uint4  b1 = *(const uint4*)(bp + 8);

        uint4 pa0, pa1;
        pa0.x = pk2(a0.x, a0.y); pa0.y = pk2(a0.z, a0.w);
        pa0.z = pk2(a1.x, a1.y); pa0.w = pk2(a1.z, a1.w);
        pa1.x = pk2(a2.x, a2.y); pa1.y = pk2(a2.z, a2.w);
        pa1.z = pk2(a3.x, a3.y); pa1.w = pk2(a3.z, a3.w);

        __syncthreads();                 // protect previous iteration's reads
        *(uint4*)&lA[r][kh]     = pa0;
        *(uint4*)&lA[r][kh + 8] = pa1;
        *(uint4*)&lB[r][kh]     = b0;
        *(uint4*)&lB[r][kh + 8] = b1;
        __syncthreads();

        s16x8 af[4], bf[4];
        #pragma unroll
        for (int f = 0; f < 4; f++) {
            af[f] = *(const s16x8*)&lA[wm * 64 + f * 16 + fr][fk];
            bf[f] = *(const s16x8*)&lB[wn * 64 + f * 16 + fr][fk];
        }
        #pragma unroll
        for (int i = 0; i < 4; i++)
            #pragma unroll
            for (int j = 0; j < 4; j++)
                acc[i][j] = __builtin_amdgcn_mfma_f32_16x16x32_bf16(af[i], bf[j], acc[i][j], 0, 0, 0);
    }

    // epilogue: C/D layout col=lane&15, row=(lane>>4)*4+q  [m89 verified, r1-validated]
    #pragma unroll
    for (int i = 0; i < 4; i++) {
        int row0 = bm * 128 + wm * 64 + i * 16 + (lane >> 4) * 4;
        #pragma unroll
        for (int j = 0; j < 4; j++) {
            int col = bn * 128 + wn * 64 + j * 16 + (lane & 15);
            float bia = bias[col];
            #pragma unroll
            for (int q = 0; q < 4; q++) {
                float v = acc[i][j][q] + bia;
                if (act) v = tanhf(v);
                Cdst[(size_t)(row0 + q) * N + col] = v;
            }
        }
    }
}

// ---------------- GRU scan: UNCHANGED from passing round 13 ------------------
__device__ __forceinline__ float fsig(float x){
    return 1.0f / (1.0f + __expf(-x));
}
__device__ __forceinline__ float ftanh(float x){
    float e = __expf(-2.0f * fabsf(x));
    float t = (1.0f - e) / (1.0f + e);
    return copysignf(t, x);
}
__device__ __forceinline__ void dot2(float& acc, u32 h2, u32 w2){
    asm("v_dot2_f32_bf16 %0, %1, %2, %0" : "+v"(acc) : "v"(h2), "v"(w2));
}

__global__ __launch_bounds__(64, 1) void k_scanb(
    const float* __restrict__ ig,   // (bch*NT,768): row lb*NT+t, col c*192+g*64+j (bias added)
    const float* __restrict__ Whh,  // layer base: (C,192,64)
    const float* __restrict__ bnp,  // (C,64)
    const float* __restrict__ lsp,  // (C)
    const float* __restrict__ h0p,  // (C,B,64) layer base
    float* __restrict__ ynew,       // layer base: (C,B,T,64) f32 (d_out)
    int b0)
{
    const int c  = blockIdx.x;
    const int lb = blockIdx.y;
    const int b  = b0 + lb;
    const int j  = threadIdx.x;     // 0..63

    u32 wr[32], wz[32], wn[32];
    {
        const float* pr = Whh + (size_t)(c * 192 +       j) * 64;
        const float* pz = Whh + (size_t)(c * 192 +  64 + j) * 64;
        const float* pn = Whh + (size_t)(c * 192 + 128 + j) * 64;
        #pragma unroll
        for (int i = 0; i < 32; i++) {
            wr[i] = (u32)f2bf(pr[2*i]) | ((u32)f2bf(pr[2*i+1]) << 16);
            wz[i] = (u32)f2bf(pz[2*i]) | ((u32)f2bf(pz[2*i+1]) << 16);
            wn[i] = (u32)f2bf(pn[2*i]) | ((u32)f2bf(pn[2*i+1]) << 16);
        }
    }

    __shared__ u32 hshb[32];        // 64 bf16 h values
    __shared__ float ring[512];     // 8 steps x 64 units
    float hj = h0p[(c * NB + b) * 64 + j];
    ((u16*)hshb)[j] = f2bf(hj);     // single wave: no barrier needed

    const float rs  = expf(-lsp[c]);     // 1/s
    const float bnj = bnp[c * 64 + j];

    const float* igp = ig + (size_t)(lb * NT) * 768 + c * 192;
    float* yrow = ynew + (size_t)(c * NB + b) * NT * 64;

    const uint4* hq = (const uint4*)hshb;

    float A0[8], A1[8], A2[8], B0[8], B1[8], B2[8];
    #pragma unroll
    for (int s = 0; s < 8; s++) {
        const float* p = igp + (size_t)s * 768;
        A0[s] = p[j]; A1[s] = p[64 + j]; A2[s] = p[128 + j];
    }

    auto step = [&](float igr, float igz, float ign, int s){
        float ar0 = 0.f, ar1 = 0.f, az0 = 0.f, az1 = 0.f, an0 = 0.f, an1 = 0.f;
        #pragma unroll
        for (int i = 0; i < 8; i++) {
            uint4 hv = hq[i];
            dot2(ar0, hv.x, wr[4*i]);     dot2(az0, hv.x, wz[4*i]);     dot2(an0, hv.x, wn[4*i]);
            dot2(ar1, hv.y, wr[4*i+1]);   dot2(az1, hv.y, wz[4*i+1]);   dot2(an1, hv.y, wn[4*i+1]);
            dot2(ar0, hv.z, wr[4*i+2]);   dot2(az0, hv.z, wz[4*i+2]);   dot2(an0, hv.z, wn[4*i+2]);
            dot2(ar1, hv.w, wr[4*i+3]);   dot2(az1, hv.w, wz[4*i+3]);   dot2(an1, hv.w, wn[4*i+3]);
        }
        float r  = fsig(igr + (ar0 + ar1));
        float z  = fsig(igz + (az0 + az1));
        float n  = ftanh(ign + r * ((an0 + an1) + bnj));
        float hn = n + z * (hj - n);
        float y  = hj + (hn - hj) * rs;     // (hn-h)/s + h
        ((u16*)hshb)[j] = f2bf(y);
        ring[s * 64 + j] = y;
        hj = y;
    };
    auto flush = [&](float* dst){
        float4 v0 = *(const float4*)&ring[4 * j];
        float4 v1 = *(const float4*)&ring[256 + 4 * j];
        *(float4*)(dst + 4 * j)       = v0;
        *(float4*)(dst + 256 + 4 * j) = v1;
    };

    for (int t0 = 0; t0 < NT; t0 += 16) {
        #pragma unroll
        for (int s = 0; s < 8; s++) {
            const float* p = igp + (size_t)(t0 + 8 + s) * 768;
            B0[s] = p[j]; B1[s] = p[64 + j]; B2[s] = p[128 + j];
        }
        #pragma unroll
        for (int s = 0; s < 8; s++) step(A0[s], A1[s], A2[s], s);
        flush(yrow + (size_t)t0 * 64);

        if (t0 + 16 < NT) {
            #pragma unroll
            for (int s = 0; s < 8; s++) {
                const float* p = igp + (size_t)(t0 + 16 + s) * 768;
                A0[s] = p[j]; A1[s] = p[64 + j]; A2[s] = p[128 + j];
            }
        }
        #pragma unroll
        for (int s = 0; s < 8; s++) step(B0[s], B1[s], B2[s], s);
        flush(yrow + (size_t)(t0 + 8) * 64);
    }
}

// ---------------- launch ----------------
extern "C" void kernel_launch(void* const* d_in, const int* in_sizes, int n_in,
                              void* d_out, int out_size, void* d_ws, size_t ws_size,
                              hipStream_t stream)
{
    const float* in_inputs = (const float*)d_in[0];
    const float* h0    = (const float*)d_in[1];
    const float* encW1 = (const float*)d_in[3];
    const float* encB1 = (const float*)d_in[4];
    const float* encW2 = (const float*)d_in[5];
    const float* encB2 = (const float*)d_in[6];
    const float* gWih  = (const float*)d_in[7];
    const float* gWhh  = (const float*)d_in[8];
    const float* gB    = (const float*)d_in[9];
    const float* gBn   = (const float*)d_in[10];
    const float* logS  = (const float*)d_in[11];
    const float* mW1   = (const float*)d_in[12];
    const float* mB1   = (const float*)d_in[13];
    const float* mW2   = (const float*)d_in[14];
    const float* mB2   = (const float*)d_in[15];

    float* out_f  = (float*)d_out;                    // (B,T,256) f32
    float* ynew_f = out_f + (size_t)MR * 256;         // (L,C,B,T,64) f32

    // ---- adaptive chunking ----
    const size_t xa_b  = (size_t)MR * 256 * 4;                 // 67.11 MB
    const size_t wb_b  = ((size_t)256*128 + 256*256 + (size_t)NL*NC*192*256
                          + 2*(size_t)NL*256*256) * 2 + 4096;  // ~2.6 MB bf16 weights
    int bch = 16;
    for (;;) {
        size_t igb = (size_t)bch * NT * 768 * 4;
        size_t r0  = igb > xa_b ? igb : xa_b;   // XB aliases region 0
        if (r0 + xa_b + wb_b + 4096 <= ws_size || bch == 1) break;
        bch >>= 1;
    }
    const int nch = NB / bch;
    const int mch = bch * NT;

    char* ws = (char*)d_ws;
    size_t off = 0;
    auto alloc = [&](size_t bytes) -> void* {
        void* p = ws + off;
        off = (off + bytes + 255) & ~(size_t)255;
        return p;
    };
    size_t igb = (size_t)bch * NT * 768 * 4;
    float* IG  = (float*)alloc(igb > xa_b ? igb : xa_b);  // region 0
    float* XB  = IG;                                       // alias: lifetimes disjoint
    float* XA  = (float*)alloc(xa_b);
    u16* WE1b  = (u16*)alloc((size_t)256 * 128 * 2);
    u16* WE2b  = (u16*)alloc((size_t)256 * 256 * 2);
    u16* WIHb  = (u16*)alloc((size_t)NL * NC * 192 * 256 * 2);
    u16* WM1b  = (u16*)alloc((size_t)NL * 256 * 256 * 2);
    u16* WM2b  = (u16*)alloc((size_t)NL * 256 * 256 * 2);

    // weight conversions (once per launch)
    k_w_to_bf16<<<(256*128 + 255) / 256, 256, 0, stream>>>(encW1, WE1b, 256*128);
    k_w_to_bf16<<<(256*256 + 255) / 256, 256, 0, stream>>>(encW2, WE2b, 256*256);
    k_w_to_bf16<<<(NL*256*256 + 255) / 256, 256, 0, stream>>>(mW1, WM1b, NL*256*256);
    k_w_to_bf16<<<(NL*256*256 + 255) / 256, 256, 0, stream>>>(mW2, WM2b, NL*256*256);
    int nWih = NL * NC * 192 * 256;
    k_scale_wih_bf16<<<(nWih + 255) / 256, 256, 0, stream>>>(gWih, logS, WIHb, nWih);

    dim3 blk(256);
    // encoder: XB = tanh(inputs @ W1^T + b1); XA = XB @ W2^T + b2
    k_gemm_mfma<0><<<dim3(MR / 128, 2), blk, 0, stream>>>(in_inputs, WE1b, encB1, XB, MR, 256, 128, 1);
    k_gemm_mfma<0><<<dim3(MR / 128, 2), blk, 0, stream>>>(XB, WE2b, encB2, XA, MR, 256, 256, 0);

    for (int l = 0; l < NL; l++) {
        float* ylayer = ynew_f + (size_t)l * NC * NB * NT * 64;
        for (int ch = 0; ch < nch; ch++) {
            k_gemm_mfma<0><<<dim3(mch / 128, 6), blk, 0, stream>>>(
                XA + (size_t)ch * mch * 256, WIHb + (size_t)l * NC * 192 * 256,
                gB + l * 768, IG, mch, 768, 256, 0);
            k_scanb<<<dim3(NC, bch), dim3(64), 0, stream>>>(
                IG, gWhh + (size_t)l * NC * 192 * 64, gBn + l * NC * 64, logS + l * NC,
                h0 + (size_t)l * NC * NB * 64, ylayer, ch * bch);
        }
        // inter-layer MLP reads A straight from ynew layout
        k_gemm_mfma<1><<<dim3(MR / 128, 2), blk, 0, stream>>>(
            ylayer, WM1b + (size_t)l * 256 * 256, mB1 + l * 256, XB, MR, 256, 256, 1);
        k_gemm_mfma<0><<<dim3(MR / 128, 2), blk, 0, stream>>>(
            XB, WM2b + (size_t)l * 256 * 256, mB2 + l * 256, XA, MR, 256, 256, 0);
    }
    // faithful to source: mlps[-1] applied a second time -> out (f32)
    k_gemm_mfma<0><<<dim3(MR / 128, 2), blk, 0, stream>>>(
        XA, WM1b + (size_t)2 * 256 * 256, mB1 + 2 * 256, XB, MR, 256, 256, 1);
    k_gemm_mfma<0><<<dim3(MR / 128, 2), blk, 0, stream>>>(
        XB, WM2b + (size_t)2 * 256 * 256, mB2 + 2 * 256, out_f, MR, 256, 256, 0);
}